// Round 16
// baseline (282.151 us; speedup 1.0000x reference)
//
#include <hip/hip_runtime.h>
#include <math.h>

// Model: B=32, C=64, T=1024, H=10, OUT=2.
// R16: SPLIT into two kernels to measure the stage/scan time split directly
// (3 scan-targeted rounds were neutral; the single-kernel profile can't
// attribute time). Kernel A (32x512): S1 embed | S2 bn+tanh+qkv stats |
// S3 M=KV^T | S4 N, prec | S5 bn+relu -> Iin to GLOBAL (coalesced per h).
// Kernel B (8x64): 4 batch-element scans PACKED PER WAVE (lanes 16g+j) --
// tests the solo-wave-latency theory: a lone wave pays ~5-6cyc/dependent
// inst; packing 4 chains into one stream amortizes it. One __ballot gives
// all 4 spike masks; per-lane mg = (bal >> 16g) & 0x3FF; terms via
// sign-extend+AND. Iin via global float4 prefetch (LLC-resident, 8 steps
// ahead); kernel-boundary release/acquire makes A's writes visible to B.

constexpr int B = 32, C = 64, T = 1024, H = 10;
constexpr int NT = 512;   // stage kernel threads (8 waves)

struct Params {
  const float *beeg, *W_ef, *b_ef, *g_i, *be_i, *Wq, *g_q, *be_q, *Wk, *g_k,
      *be_k, *Wv, *g_v, *be_v, *Wc, *g_c, *be_c, *W_in, *W_rec, *W_cls, *b_cls;
  int* cnt;              // barrier counters (memset 0 each launch)
  double *P1, *P2, *P3;  // cross-block stat partials, layout [ch][32]
  float* IinG;           // [b][h][1024] input currents (global)
  float* out;
};

// DPP wave64 sum helpers (VALU pipe). row_* ops act within 16-lane rows.
template <int CTRL>
__device__ inline float dadd(float v) {
  int x = __builtin_amdgcn_update_dpp(0, __float_as_int(v), CTRL, 0xf, 0xf,
                                      true);
  return v + __int_as_float(x);
}
__device__ inline float wred63(float v) {       // full-wave sum -> lane 63
  v = dadd<0x111>(v); v = dadd<0x112>(v); v = dadd<0x114>(v);
  v = dadd<0x118>(v); v = dadd<0x142>(v); v = dadd<0x143>(v);
  return v;
}
__device__ inline float rowred15(float v) {     // 16-lane row sum -> lane 15
  v = dadd<0x111>(v); v = dadd<0x112>(v); v = dadd<0x114>(v);
  v = dadd<0x118>(v);
  return v;
}

// 32-block barrier, fence-free (all cross-block data via agent-scope atomics).
__device__ inline void gbar(int* cnt, int phase, int tid) {
  __syncthreads();
  if (tid == 0) {
    __hip_atomic_fetch_add(&cnt[phase], 1, __ATOMIC_RELEASE,
                           __HIP_MEMORY_SCOPE_AGENT);
    while (__hip_atomic_load(&cnt[phase], __ATOMIC_RELAXED,
                             __HIP_MEMORY_SCOPE_AGENT) < B)
      __builtin_amdgcn_s_sleep(2);
  }
  __syncthreads();
}

// ======================= Kernel A: stages =======================
__global__ void __launch_bounds__(NT) stagesA(Params p) {
  const int b = blockIdx.x, tid = threadIdx.x;
  const int lane = tid & 63, wid = tid >> 6;   // 8 waves
  const int t0 = tid, t1 = tid + NT;

  // LDS ~54.6KB => 2 WGs/CU by the occupancy heuristic => 4 waves/EU
  // => 128-VGPR budget (no-spill regime of R8-R15).
  __shared__ __align__(16) float slab[T * 11];   // scratch only now
  __shared__ double dred2[60 * 17 + 4];
  __shared__ double dtot[60];
  __shared__ float stM[30], stI[30], Ms[100], Nl[100];

  float* swred = slab;         // [8][60] stats scratch
  float* mpw   = slab + 512;   // [8][100] M partials

  // parallel stats combine: P layout [ch][32]; ch x 16 workers, 2 loads each.
  auto combine = [&](double* P, int Q2) {
    for (int id = tid; id < Q2 * 16; id += NT) {
      int ch = id >> 4, i = id & 15;
      double s = __hip_atomic_load(&P[ch * 32 + i], __ATOMIC_RELAXED,
                                   __HIP_MEMORY_SCOPE_AGENT) +
                 __hip_atomic_load(&P[ch * 32 + 16 + i], __ATOMIC_RELAXED,
                                   __HIP_MEMORY_SCOPE_AGENT);
      dred2[ch * 17 + i] = s;
    }
    __syncthreads();
    if (tid < Q2) {
      double s = 0.0;
#pragma unroll
      for (int i = 0; i < 16; ++i) s += dred2[tid * 17 + i];
      dtot[tid] = s;
    }
    __syncthreads();
  };

  // ---------------- S1: embed (weights via uniform/scalar loads)
  float p1a[H], p1b[H];
#pragma unroll
  for (int h = 0; h < H; ++h) { p1a[h] = p.b_ef[h]; p1b[h] = p.b_ef[h]; }
  {
    const float* bp = p.beeg + (size_t)b * C * T;
#pragma unroll 8
    for (int c = 0; c < C; ++c) {
      float va = bp[(size_t)c * T + t0];
      float vb = bp[(size_t)c * T + t1];
#pragma unroll
      for (int h = 0; h < H; ++h) {
        float w = p.W_ef[h * C + c];   // wave-uniform -> s_load
        p1a[h] = fmaf(va, w, p1a[h]);
        p1b[h] = fmaf(vb, w, p1b[h]);
      }
    }
  }
#pragma unroll
  for (int h = 0; h < H; ++h) {
    float r1 = wred63(p1a[h] + p1b[h]);
    float r2 = wred63(p1a[h] * p1a[h] + p1b[h] * p1b[h]);
    if (lane == 63) { swred[wid * 60 + h] = r1; swred[wid * 60 + 10 + h] = r2; }
  }
  __syncthreads();
  if (tid < 20) {
    float s = 0.f;
#pragma unroll
    for (int w = 0; w < 8; ++w) s += swred[w * 60 + tid];
    __hip_atomic_store(&p.P1[tid * 32 + b], (double)s, __ATOMIC_RELAXED,
                       __HIP_MEMORY_SCOPE_AGENT);
  }
  gbar(p.cnt, 0, tid);
  combine(p.P1, 20);
  if (tid < 10) {
    double mean = dtot[tid] * (1.0 / 32768.0);
    double var  = dtot[10 + tid] * (1.0 / 32768.0) - mean * mean;
    stM[tid] = (float)mean;
    stI[tid] = (float)(1.0 / sqrt(var + 1e-5));
  }
  __syncthreads();

  // ---------------- S2
  float xa[H], xb[H];
#pragma unroll
  for (int j = 0; j < H; ++j) {
    xa[j] = tanhf(p.g_i[j] * (p1a[j] - stM[j]) * stI[j] + p.be_i[j]);
    xb[j] = tanhf(p.g_i[j] * (p1b[j] - stM[j]) * stI[j] + p.be_i[j]);
  }
#pragma unroll
  for (int h = 0; h < H; ++h) {
    float qa = 0.f, qb = 0.f, ka = 0.f, kb = 0.f, va = 0.f, vb = 0.f;
#pragma unroll
    for (int j = 0; j < H; ++j) {
      float wq = p.Wq[h * H + j], wk = p.Wk[h * H + j], wv = p.Wv[h * H + j];
      qa = fmaf(xa[j], wq, qa); qb = fmaf(xb[j], wq, qb);
      ka = fmaf(xa[j], wk, ka); kb = fmaf(xb[j], wk, kb);
      va = fmaf(xa[j], wv, va); vb = fmaf(xb[j], wv, vb);
    }
    float r1 = wred63(qa + qb), r2 = wred63(qa * qa + qb * qb);
    float r3 = wred63(ka + kb), r4 = wred63(ka * ka + kb * kb);
    float r5 = wred63(va + vb), r6 = wred63(va * va + vb * vb);
    if (lane == 63) {
      swred[wid * 60 + h]      = r1; swred[wid * 60 + 30 + h] = r2;
      swred[wid * 60 + 10 + h] = r3; swred[wid * 60 + 40 + h] = r4;
      swred[wid * 60 + 20 + h] = r5; swred[wid * 60 + 50 + h] = r6;
    }
  }
  __syncthreads();
  if (tid < 60) {
    float s = 0.f;
#pragma unroll
    for (int w = 0; w < 8; ++w) s += swred[w * 60 + tid];
    __hip_atomic_store(&p.P2[tid * 32 + b], (double)s, __ATOMIC_RELAXED,
                       __HIP_MEMORY_SCOPE_AGENT);
  }
  gbar(p.cnt, 1, tid);
  combine(p.P2, 60);
  if (tid < 30) {
    double mean = dtot[tid] * (1.0 / 32768.0);
    double var  = dtot[30 + tid] * (1.0 / 32768.0) - mean * mean;
    stM[tid] = (float)mean;
    stI[tid] = (float)(1.0 / sqrt(var + 1e-5));
  }
  __syncthreads();

  // ---------------- S3: M = KV^T in two sequential passes
  {
    float kx[H], vx[H];
#pragma unroll
    for (int h = 0; h < H; ++h) {
      float ka = 0.f, va = 0.f;
#pragma unroll
      for (int j = 0; j < H; ++j) {
        ka = fmaf(xa[j], p.Wk[h * H + j], ka);
        va = fmaf(xa[j], p.Wv[h * H + j], va);
      }
      kx[h] = fmaxf(p.g_k[h] * (ka - stM[10 + h]) * stI[10 + h] + p.be_k[h], 0.f);
      vx[h] = tanhf(p.g_v[h] * (va - stM[20 + h]) * stI[20 + h] + p.be_v[h]);
    }
#pragma unroll
    for (int i = 0; i < H; ++i)
#pragma unroll
      for (int j = 0; j < H; ++j) {
        float r = wred63(kx[i] * vx[j]);
        if (lane == 63) mpw[wid * 100 + i * 10 + j] = r;
      }
  }
  {
    float kx[H], vx[H];
#pragma unroll
    for (int h = 0; h < H; ++h) {
      float kb = 0.f, vb = 0.f;
#pragma unroll
      for (int j = 0; j < H; ++j) {
        kb = fmaf(xb[j], p.Wk[h * H + j], kb);
        vb = fmaf(xb[j], p.Wv[h * H + j], vb);
      }
      kx[h] = fmaxf(p.g_k[h] * (kb - stM[10 + h]) * stI[10 + h] + p.be_k[h], 0.f);
      vx[h] = tanhf(p.g_v[h] * (vb - stM[20 + h]) * stI[20 + h] + p.be_v[h]);
    }
#pragma unroll
    for (int i = 0; i < H; ++i)
#pragma unroll
      for (int j = 0; j < H; ++j) {
        float r = wred63(kx[i] * vx[j]);
        if (lane == 63) mpw[wid * 100 + i * 10 + j] += r;
      }
  }
  __syncthreads();
  if (tid < 100) {
    float s = 0.f;
#pragma unroll
    for (int w = 0; w < 8; ++w) s += mpw[w * 100 + tid];
    Ms[tid] = s;
  }
  __syncthreads();

  // ---------------- S4
  if (tid < 100) {
    int i = tid / 10, h = tid % 10;
    float a = 0.f;
#pragma unroll
    for (int j = 0; j < H; ++j) a = fmaf(Ms[i * 10 + j], p.Wc[h * H + j], a);
    Nl[tid] = a * 0.1f;
  }
  __syncthreads();
  float pca[H], pcb[H];
  {
    float qv[H];
#pragma unroll
    for (int h = 0; h < H; ++h) {
      float qa = 0.f;
#pragma unroll
      for (int j = 0; j < H; ++j) qa = fmaf(xa[j], p.Wq[h * H + j], qa);
      qv[h] = fmaxf(p.g_q[h] * (qa - stM[h]) * stI[h] + p.be_q[h], 0.f);
    }
#pragma unroll
    for (int h = 0; h < H; ++h) {
      float a = 0.f;
#pragma unroll
      for (int i = 0; i < H; ++i) a = fmaf(qv[i], Nl[i * 10 + h], a);
      pca[h] = a;
    }
  }
  {
    float qv[H];
#pragma unroll
    for (int h = 0; h < H; ++h) {
      float qb = 0.f;
#pragma unroll
      for (int j = 0; j < H; ++j) qb = fmaf(xb[j], p.Wq[h * H + j], qb);
      qv[h] = fmaxf(p.g_q[h] * (qb - stM[h]) * stI[h] + p.be_q[h], 0.f);
    }
#pragma unroll
    for (int h = 0; h < H; ++h) {
      float a = 0.f;
#pragma unroll
      for (int i = 0; i < H; ++i) a = fmaf(qv[i], Nl[i * 10 + h], a);
      pcb[h] = a;
    }
  }
#pragma unroll
  for (int h = 0; h < H; ++h) {
    float r1 = wred63(pca[h] + pcb[h]);
    float r2 = wred63(pca[h] * pca[h] + pcb[h] * pcb[h]);
    if (lane == 63) { swred[wid * 60 + h] = r1; swred[wid * 60 + 10 + h] = r2; }
  }
  __syncthreads();
  if (tid < 20) {
    float s = 0.f;
#pragma unroll
    for (int w = 0; w < 8; ++w) s += swred[w * 60 + tid];
    __hip_atomic_store(&p.P3[tid * 32 + b], (double)s, __ATOMIC_RELAXED,
                       __HIP_MEMORY_SCOPE_AGENT);
  }
  gbar(p.cnt, 2, tid);
  combine(p.P3, 20);
  if (tid < 10) {
    double mean = dtot[tid] * (1.0 / 32768.0);
    double var  = dtot[10 + tid] * (1.0 / 32768.0) - mean * mean;
    stM[tid] = (float)mean;
    stI[tid] = (float)(1.0 / sqrt(var + 1e-5));
  }
  __syncthreads();

  // ---------------- S5: bn+relu, Iin -> GLOBAL [b][h][1024], coalesced per h
  {
    float* dst = p.IinG + (size_t)b * (H * 1024);
    float ca[H];
#pragma unroll
    for (int j = 0; j < H; ++j)
      ca[j] = fmaxf(p.g_c[j] * (pca[j] - stM[j]) * stI[j] + p.be_c[j], 0.f);
#pragma unroll
    for (int h = 0; h < H; ++h) {
      float a = 0.f;
#pragma unroll
      for (int j = 0; j < H; ++j) a = fmaf(ca[j], p.W_in[h * H + j], a);
      dst[h * 1024 + t0] = a;
    }
#pragma unroll
    for (int j = 0; j < H; ++j)
      ca[j] = fmaxf(p.g_c[j] * (pcb[j] - stM[j]) * stI[j] + p.be_c[j], 0.f);
#pragma unroll
    for (int h = 0; h < H; ++h) {
      float a = 0.f;
#pragma unroll
      for (int j = 0; j < H; ++j) a = fmaf(ca[j], p.W_in[h * H + j], a);
      dst[h * 1024 + t1] = a;
    }
  }
}

// ======================= Kernel B: 4-way packed LSNN scan =======================
__global__ void __launch_bounds__(64) k_scan4(Params p) {
  const int lane = threadIdx.x;
  const int g = lane >> 4, j = lane & 15;    // group (batch) / channel slot
  const bool act = j < H;
  const int bb = (blockIdx.x << 2) | g;

  // 40KB LDS (only [0..1023] used) => 4 blocks/CU => 1 wave/EU => full VGPR
  // budget (avoids the 64-VGPR small-LDS trap of R4-R7).
  __shared__ __align__(16) float gtab[10240];
  {
    const float L2A = -0.15200309344504995f;   // log2(0.9)
    const float L2D = -0.32192809488736235f;   // log2(0.8)
    for (int i = lane; i < T; i += 64) {
      float m1 = (float)(T - i);
      gtab[i] = (9.0f * (1.0f - exp2f(m1 * L2A)) -
                 4.0f * (1.0f - exp2f(m1 * L2D))) * (1.0f / (float)T);
    }
  }
  __syncthreads();

  const float gtot = 4.9365234375f;  // closed form (0.9^1024/0.8^1024 underflow)
  const float* rowp = p.IinG + (size_t)bb * (H * 1024) +
                      (size_t)(act ? j : (H - 1)) * 1024;
  int wri[H];
#pragma unroll
  for (int jj = 0; jj < H; ++jj)
    wri[jj] = act ? __float_as_int(p.W_rec[j * H + jj]) : 0;
  float wc0 = act ? p.W_cls[j] : 0.f;
  float wc1 = act ? p.W_cls[H + j] : 0.f;

  float cur = 0.f, vm = 0.f, S = 0.f;
  unsigned long long bal = 0ull;
  const int sh = g << 4;

  auto step = [&](float iin, float gt) {
    int m = (int)((unsigned)(bal >> sh) & 0x3FFu);   // group's 10 spike bits
    float tA0 = __int_as_float(((m << 31) >> 31) & wri[0]);
    float tA1 = __int_as_float(((m << 30) >> 31) & wri[1]);
    float tA2 = __int_as_float(((m << 29) >> 31) & wri[2]);
    float tA3 = __int_as_float(((m << 28) >> 31) & wri[3]);
    float tA4 = __int_as_float(((m << 27) >> 31) & wri[4]);
    float tA5 = __int_as_float(((m << 26) >> 31) & wri[5]);
    float tA6 = __int_as_float(((m << 25) >> 31) & wri[6]);
    float tA7 = __int_as_float(((m << 24) >> 31) & wri[7]);
    float tA8 = __int_as_float(((m << 23) >> 31) & wri[8]);
    float tA9 = __int_as_float(((m << 22) >> 31) & wri[9]);
    float p01 = tA0 + tA1, p23 = tA2 + tA3, p45 = tA4 + tA5;
    float p67 = tA6 + tA7, p89 = tA8 + tA9;
    float rec = ((p01 + p23) + (p45 + p67)) + p89;
    float i_jump = (cur + iin) + rec;
    float v_dec = fmaf(0.1f, i_jump - vm, vm);   // vm + 0.1*(i_jump - vm)
    cur = 0.8f * i_jump;                         // i_dec
    bool z = v_dec > 0.5f;                       // lanes j>=10: masked out of m
    vm = z ? 0.f : v_dec;
    S += z ? gt : 0.f;                           // j>=10 lanes: wc==0 anyway
    bal = __ballot(z);
  };

  float4 iA = *(const float4*)&rowp[0];
  float4 iB = *(const float4*)&rowp[4];
  float4 gA = *(const float4*)&gtab[0], gB = *(const float4*)&gtab[4];

  for (int t8 = 0; t8 < T - 8; t8 += 8) {
    float4 iN1 = *(const float4*)&rowp[t8 + 8];
    float4 iN2 = *(const float4*)&rowp[t8 + 12];
    float4 gN1 = *(const float4*)&gtab[t8 + 8];
    float4 gN2 = *(const float4*)&gtab[t8 + 12];
    step(iA.x, gA.x); step(iA.y, gA.y); step(iA.z, gA.z); step(iA.w, gA.w);
    step(iB.x, gB.x); step(iB.y, gB.y); step(iB.z, gB.z); step(iB.w, gB.w);
    iA = iN1; iB = iN2; gA = gN1; gB = gN2;
  }
  step(iA.x, gA.x); step(iA.y, gA.y); step(iA.z, gA.z); step(iA.w, gA.w);
  step(iB.x, gB.x); step(iB.y, gB.y); step(iB.z, gB.z); step(iB.w, gB.w);

  // classifier: 16-lane row reduce (groups are DPP rows), lane j==15 writes
  float c0 = rowred15(S * wc0);
  float c1 = rowred15(S * wc1);
  if (j == 15) {
    p.out[bb * 2 + 0] = c0 + gtot * p.b_cls[0];
    p.out[bb * 2 + 1] = c1 + gtot * p.b_cls[1];
  }
}

extern "C" void kernel_launch(void* const* d_in, const int* in_sizes, int n_in,
                              void* d_out, int out_size, void* d_ws, size_t ws_size,
                              hipStream_t stream) {
  Params p;
  p.beeg  = (const float*)d_in[2];
  p.W_ef  = (const float*)d_in[4];
  p.b_ef  = (const float*)d_in[5];
  p.g_i   = (const float*)d_in[6];
  p.be_i  = (const float*)d_in[7];
  p.Wq    = (const float*)d_in[8];
  p.g_q   = (const float*)d_in[9];
  p.be_q  = (const float*)d_in[10];
  p.Wk    = (const float*)d_in[11];
  p.g_k   = (const float*)d_in[12];
  p.be_k  = (const float*)d_in[13];
  p.Wv    = (const float*)d_in[14];
  p.g_v   = (const float*)d_in[15];
  p.be_v  = (const float*)d_in[16];
  p.Wc    = (const float*)d_in[17];
  p.g_c   = (const float*)d_in[18];
  p.be_c  = (const float*)d_in[19];
  p.W_in  = (const float*)d_in[20];
  p.W_rec = (const float*)d_in[21];
  p.W_cls = (const float*)d_in[22];
  p.b_cls = (const float*)d_in[23];

  char* ws = (char*)d_ws;
  p.cnt  = (int*)ws;                            // 3 counters, memset below
  p.P1   = (double*)(ws + 256);                 // [20][32] doubles
  p.P2   = (double*)(ws + 256 + 5120);          // [60][32] doubles
  p.P3   = (double*)(ws + 256 + 5120 + 15360);  // [20][32] doubles
  p.IinG = (float*)(ws + 32768);                // 32*10*1024 floats (1.31MB)
  p.out  = (float*)d_out;

  (void)hipMemsetAsync(d_ws, 0, 256, stream);  // zero barrier counters
  stagesA<<<dim3(B), dim3(NT), 0, stream>>>(p);
  k_scan4<<<dim3(8), dim3(64), 0, stream>>>(p);
}